// Round 5
// baseline (449.918 us; speedup 1.0000x reference)
//
#include <hip/hip_runtime.h>
#include <math.h>

namespace {

constexpr int C_ = 3, T_ = 3000, F_ = 103, NB_ = 6;
constexpr int TT = 20;                        // 3000/20 = 150 blocks along T
constexpr int BS_[NB_]  = {1, 10, 20, 30, 40, 61};
constexpr int BNB_[NB_] = {10, 11, 11, 11, 22, 16};
constexpr int BP_[NB_]  = {12, 12, 12, 12, 24, 16};   // padded to x4
constexpr int BPS_[NB_] = {0, 12, 24, 36, 48, 72};    // cumsum BP, total 88
constexpr int WOFP_[NB_] = {0, 216, 432, 648, 864, 1296}; // cumsum 18*BP
constexpr int WTOTP = 1584;                   // padded gaussian weights
constexpr int SLOTS = 88;                     // band-sliced cols per (c,tt)
constexpr int CTSTR = 92;                     // padded stride (92%32=28 -> 8-cyc optimal b128)
constexpr int SPECN = C_ * TT * CTSTR;        // 5520
constexpr int PLANE = T_ * F_;                // 309000
constexpr int SEC  = TT * F_;                 // 2060
constexpr int SECP = 2064;                    // enh plane stride (x4)
constexpr int POOLN = SPECN + WTOTP;          // 7104 >= 3*SECP=6192 (alias for enh)
constexpr int NTHR = 384;

__device__ __forceinline__ float softplus_full_(float x) {
  return fmaxf(x, 0.0f) + log1pf(expf(-fabsf(x)));
}
__device__ __forceinline__ float sigmoid_(float z) {
  return 1.0f / (1.0f + __expf(-z));
}
__device__ __forceinline__ float gelu_(float x) {
  return x * sigmoid_(1.595769122f * x * (1.0f + 0.044715f * x * x));
}

// ---- pre-kernel: padded gaussian bank + folded proj/BN -> d_ws ----------------
// d_ws layout (floats): [0..1583] weights, [1584..1592] projBN w, [1593..1595] projBN b
__global__ __launch_bounds__(128)
void prep_kernel(const float* __restrict__ centers,
                 const float* __restrict__ widths,
                 const float* __restrict__ gains,
                 const float* __restrict__ proj_w,
                 const float* __restrict__ proj_b,
                 const float* __restrict__ bn_gamma,
                 const float* __restrict__ bn_beta,
                 const float* __restrict__ bn_mean,
                 const float* __restrict__ bn_var,
                 float* __restrict__ ws)
{
  const int q = threadIdx.x;
  if (q < 108) {
    int i = q / 18;
    int p = q - i * 18;
    int s = BS_[i], nb = BNB_[i];
    float mu = softplus_full_(centers[q]) + (float)s;
    mu = fminf(fmaxf(mu, (float)s), (float)(s + nb - 1));
    float sd = softplus_full_(widths[q]) + 0.001f;
    sd = fminf(fmaxf(sd, 0.5f), 2.0f * (float)nb / 6.0f);
    float sum = 0.0f;
    for (int f = 0; f < nb; ++f) {
      float d = ((float)f - mu) / sd;
      sum += __expf(-0.5f * d * d);
    }
    float sc = gains[q] / (sum + 1e-6f);
    float* wrow = &ws[WOFP_[i] + p * BP_[i]];
    for (int f = 0; f < nb; ++f) {
      float d = ((float)f - mu) / sd;
      wrow[f] = sc * __expf(-0.5f * d * d);
    }
    for (int f = nb; f < BP_[i]; ++f) wrow[f] = 0.0f;   // zero pads (NaN-safe)
  } else if (q < 117) {
    int k = q - 108, d = k / 3;
    float sc = bn_gamma[d] / sqrtf(bn_var[d] + 1e-5f);
    ws[WTOTP + k] = proj_w[k] * sc;
  } else if (q < 120) {
    int d = q - 117;
    float sc = bn_gamma[d] / sqrtf(bn_var[d] + 1e-5f);
    ws[WTOTP + 9 + d] = (proj_b[d] - bn_mean[d]) * sc + bn_beta[d];
  }
}

// ---- main kernel --------------------------------------------------------------
__global__ __launch_bounds__(NTHR, 6)
void sleepband_kernel(const float* __restrict__ spec,
                      const float* __restrict__ ws,
                      const float* __restrict__ align_w,
                      const float* __restrict__ align_b,
                      const float* __restrict__ fc1_w,
                      const float* __restrict__ fc1_b,
                      const float* __restrict__ fc2_w,
                      const float* __restrict__ fc2_b,
                      const float* __restrict__ band_gain,
                      const float* __restrict__ gate_w,
                      const float* __restrict__ gate_b,
                      float* __restrict__ out)
{
  // pool: [stage/A] sSpecB[60][92] (5520) + sWB (1584)  ||  [B2/final] enh[3][SECP]
  __shared__ __align__(16) float sPool[POOLN];
  __shared__ float sBand[TT][109];   // odd stride -> conflict-free

  const int tid = threadIdx.x;
  const int t0  = blockIdx.x * TT;
  const int b   = blockIdx.y;
  const float* specB = spec + (size_t)b * C_ * PLANE;

  // ---- stage spec, band-sliced + padded (roughly coalesced; dup bins L1-hot) ----
  for (int li = tid; li < C_ * TT * SLOTS; li += NTHR) {
    int ctt  = li / SLOTS;
    int slot = li - ctt * SLOTS;
    int c    = ctt / TT;
    int tt   = ctt - c * TT;
    int i    = (slot >= 72) ? 5 : ((slot >= 48) ? 4 : (slot / 12));
    int j    = slot - BPS_[i];
    float v  = 0.0f;
    if (j < BNB_[i])
      v = specB[(size_t)c * PLANE + (size_t)(t0 + tt) * F_ + (BS_[i] + j)];
    sPool[ctt * CTSTR + slot] = v;
  }
  // stage padded gaussian weights (L2-hot)
  for (int k = tid; k < WTOTP; k += NTHR) sPool[SPECN + k] = ws[k];
  __syncthreads();

  // ---- Phase A: filt via float4 MAC (360 tasks) ----
  if (tid < 18 * TT) {
    const int p  = tid / TT;
    const int tt = tid - p * TT;
    const int c  = p / 6;
    const int n  = p - c * 6;
    const float* srow = &sPool[(c * TT + tt) * CTSTR];
    const float* wall = &sPool[SPECN];
    #pragma unroll
    for (int i = 0; i < NB_; ++i) {
      const float4* s4 = (const float4*)(srow + BPS_[i]);
      const float4* w4 = (const float4*)(wall + WOFP_[i] + p * BP_[i]);
      float4 a = {0.0f, 0.0f, 0.0f, 0.0f};
      #pragma unroll
      for (int k = 0; k < BP_[i] / 4; ++k) {
        float4 sv = s4[k], wv = w4[k];
        a.x += sv.x * wv.x; a.y += sv.y * wv.y;
        a.z += sv.z * wv.z; a.w += sv.w * wv.w;
      }
      sBand[tt][(i * 3 + c) * 6 + n] = (a.x + a.y) + (a.z + a.w);
    }
  }
  __syncthreads();

  // ---- Phase B: align + MLP + softmax + scale (120 tasks; weights via s_load) ----
  if (tid < 6 * TT) {
    const int n  = tid / TT;
    const int tt = tid - n * TT;
    float al[18];
    #pragma unroll
    for (int i = 0; i < 6; ++i) {
      float f0 = sBand[tt][(i * 3 + 0) * 6 + n];
      float f1 = sBand[tt][(i * 3 + 1) * 6 + n];
      float f2 = sBand[tt][(i * 3 + 2) * 6 + n];
      #pragma unroll
      for (int d = 0; d < 3; ++d)
        al[i * 3 + d] = align_w[i * 9 + d * 3 + 0] * f0 + align_w[i * 9 + d * 3 + 1] * f1 +
                        align_w[i * 9 + d * 3 + 2] * f2 + align_b[i * 3 + d];
    }
    float h[6];
    #pragma unroll
    for (int o = 0; o < 6; ++o) {
      float acc = fc1_b[o];
      #pragma unroll
      for (int k = 0; k < 18; ++k) acc += fc1_w[o * 18 + k] * al[k];
      h[o] = gelu_(acc);
    }
    float at[18];
    #pragma unroll
    for (int k = 0; k < 18; ++k) {
      float acc = fc2_b[k];
      #pragma unroll
      for (int o = 0; o < 6; ++o) acc += fc2_w[k * 6 + o] * h[o];
      at[k] = acc;
    }
    #pragma unroll
    for (int c = 0; c < 3; ++c) {
      float m = at[c];
      #pragma unroll
      for (int i = 1; i < 6; ++i) m = fmaxf(m, at[i * 3 + c]);
      float e[6], ssum = 0.0f;
      #pragma unroll
      for (int i = 0; i < 6; ++i) { e[i] = __expf(at[i * 3 + c] - m); ssum += e[i]; }
      float inv = 1.0f / ssum;
      #pragma unroll
      for (int i = 0; i < 6; ++i)
        sBand[tt][(i * 3 + c) * 6 + n] = al[i * 3 + c] * (e[i] * inv) * band_gain[i];
    }
  }
  __syncthreads();

  // ---- Phase B2: compile-time-tap upsample into dense enh (60 tasks) ----
  if (tid < C_ * TT) {
    const int c  = tid / TT;
    const int tt = tid - c * TT;
    float bnd[36];
    #pragma unroll
    for (int i = 0; i < 6; ++i)
      #pragma unroll
      for (int n = 0; n < 6; ++n)
        bnd[i * 6 + n] = sBand[tt][(i * 3 + c) * 6 + n];
    float* row = &sPool[c * SECP + tt * F_];
    row[0] = 0.0f;
    float carry = 0.0f;
    #pragma unroll
    for (int i = 0; i < NB_; ++i) {
      #pragma unroll
      for (int j = 0; j < BNB_[i]; ++j) {
        float src = ((float)j + 0.5f) * 6.0f / (float)BNB_[i] - 0.5f;
        src = src > 0.0f ? src : 0.0f;
        int   x0 = (int)src;
        int   x1 = (x0 < 5) ? x0 + 1 : 5;
        float wl = src - (float)x0;
        float v  = bnd[i * 6 + x0] * (1.0f - wl) + bnd[i * 6 + x1] * wl;
        if (j == 0) v += carry;
        if (i < NB_ - 1 && j == BNB_[i] - 1) carry = v;
        else row[BS_[i] + j] = v;
      }
    }
    #pragma unroll
    for (int f = 77; f < F_; ++f) row[f] = 0.0f;
  }
  __syncthreads();

  // ---- Final: flat float4 gate + folded proj + gelu (uniform params -> SGPR) ----
  float gw[9], pw[9], gb3[3], pb3[3];
  #pragma unroll
  for (int k = 0; k < 9; ++k) { gw[k] = gate_w[k]; pw[k] = ws[WTOTP + k]; }
  #pragma unroll
  for (int k = 0; k < 3; ++k) { gb3[k] = gate_b[k]; pb3[k] = ws[WTOTP + 9 + k]; }

  const float* sp0 = specB + (size_t)t0 * F_;
  float* outB = out + (size_t)b * C_ * PLANE + (size_t)t0 * F_;
  for (int e4 = tid; e4 < SEC / 4; e4 += NTHR) {
    const int e = e4 * 4;
    const float4 sA = *(const float4*)(sp0 + e);
    const float4 sB = *(const float4*)(sp0 + PLANE + e);
    const float4 sC = *(const float4*)(sp0 + 2 * PLANE + e);
    const float4 eA = *(const float4*)&sPool[0 * SECP + e];
    const float4 eB = *(const float4*)&sPool[1 * SECP + e];
    const float4 eC = *(const float4*)&sPool[2 * SECP + e];
    float4 oA, oB, oC;
    const float* sAp = (const float*)&sA; const float* sBp = (const float*)&sB;
    const float* sCp = (const float*)&sC;
    const float* eAp = (const float*)&eA; const float* eBp = (const float*)&eB;
    const float* eCp = (const float*)&eC;
    float* oAp = (float*)&oA; float* oBp = (float*)&oB; float* oCp = (float*)&oC;
    #pragma unroll
    for (int j = 0; j < 4; ++j) {
      float sv0 = sAp[j], sv1 = sBp[j], sv2 = sCp[j];
      float r0 = eAp[j] - sv0, r1 = eBp[j] - sv1, r2 = eCp[j] - sv2;
      float e20 = sv0 + sigmoid_(gw[0] * r0 + gw[1] * r1 + gw[2] * r2 + gb3[0]) * r0;
      float e21 = sv1 + sigmoid_(gw[3] * r0 + gw[4] * r1 + gw[5] * r2 + gb3[1]) * r1;
      float e22 = sv2 + sigmoid_(gw[6] * r0 + gw[7] * r1 + gw[8] * r2 + gb3[2]) * r2;
      float y0 = pw[0] * e20 + pw[1] * e21 + pw[2] * e22 + pb3[0];
      float y1 = pw[3] * e20 + pw[4] * e21 + pw[5] * e22 + pb3[1];
      float y2 = pw[6] * e20 + pw[7] * e21 + pw[8] * e22 + pb3[2];
      oAp[j] = gelu_(y0); oBp[j] = gelu_(y1); oCp[j] = gelu_(y2);
    }
    *(float4*)(outB + e) = oA;
    *(float4*)(outB + PLANE + e) = oB;
    *(float4*)(outB + 2 * PLANE + e) = oC;
  }
}

} // namespace

extern "C" void kernel_launch(void* const* d_in, const int* in_sizes, int n_in,
                              void* d_out, int out_size, void* d_ws, size_t ws_size,
                              hipStream_t stream) {
  (void)n_in; (void)out_size; (void)ws_size;
  const int B = in_sizes[0] / (C_ * T_ * F_);   // 64
  float* ws = (float*)d_ws;                     // 1596 floats used
  prep_kernel<<<1, 128, 0, stream>>>(
      (const float*)d_in[1],  (const float*)d_in[2],  (const float*)d_in[3],
      (const float*)d_in[13], (const float*)d_in[14], (const float*)d_in[15],
      (const float*)d_in[16], (const float*)d_in[17], (const float*)d_in[18], ws);
  dim3 grid(T_ / TT, B);                        // (150, 64)
  sleepband_kernel<<<grid, NTHR, 0, stream>>>(
      (const float*)d_in[0],  ws,
      (const float*)d_in[4],  (const float*)d_in[5],
      (const float*)d_in[6],  (const float*)d_in[7],  (const float*)d_in[8],
      (const float*)d_in[9],  (const float*)d_in[10], (const float*)d_in[11],
      (const float*)d_in[12], (float*)d_out);
}